// Round 12
// baseline (321.496 us; speedup 1.0000x reference)
//
#include <hip/hip_runtime.h>
#include <hip/hip_bf16.h>

// Problem constants
#define B_  32
#define NI_ 1024
#define NT_ 512
#define D_  1024

typedef __attribute__((ext_vector_type(8))) short bf16x8;   // 8 bf16 = 4 VGPRs
typedef __attribute__((ext_vector_type(4))) float f32x4;    // MFMA accumulator

// round-to-nearest-even f32 -> bf16 (values are finite here)
__device__ __forceinline__ ushort f2b(float f) {
  unsigned u = __builtin_bit_cast(unsigned, f);
  u = (u + 0x7FFFu + ((u >> 16) & 1u)) >> 16;
  return (ushort)u;
}

// ---------------------------------------------------------------------------
// LDS tile scheme (XOR-swizzled chunk order; bank-verified R6/R7):
//   A [rows][32] bf16 tile is 16-row blocks of 64 16B-chunks.
//   Staging thread t writes at wpos = ((t>>6)<<6) | (((t>>2)&15)<<2)
//     | ((t&3) ^ ((t>>3)&3)).   (valid for any #rows = multiple of 16)
//   MFMA frag read lane l, block bi: chunk = bi*64 + chunkLane,
//     chunkLane = ((l&15)<<2) | ((l>>4) ^ ((l>>1)&3)).
//   Both ds_write_b128 and ds_read_b128 conflict-free.
// ---------------------------------------------------------------------------

// ---------------------------------------------------------------------------
// LayerNorm over D=1024, fp32 in -> bf16 out. One wave per row, 4 rows/block.
// ---------------------------------------------------------------------------
__global__ __launch_bounds__(256) void ln_bf16_kernel(
    const float* __restrict__ x, const float* __restrict__ gamma,
    const float* __restrict__ beta, ushort* __restrict__ out)
{
  const int row  = blockIdx.x * 4 + (threadIdx.x >> 6);
  const int lane = threadIdx.x & 63;
  const float* xr = x + (size_t)row * D_;
  float4 v[4];
  float s = 0.f, sq = 0.f;
#pragma unroll
  for (int q = 0; q < 4; ++q) {
    v[q] = *reinterpret_cast<const float4*>(xr + q * 256 + lane * 4);
    s  += v[q].x + v[q].y + v[q].z + v[q].w;
    sq += v[q].x*v[q].x + v[q].y*v[q].y + v[q].z*v[q].z + v[q].w*v[q].w;
  }
#pragma unroll
  for (int m = 1; m < 64; m <<= 1) {
    s  += __shfl_xor(s,  m);
    sq += __shfl_xor(sq, m);
  }
  const float mean = s * (1.f / D_);
  const float rstd = rsqrtf(sq * (1.f / D_) - mean * mean + 1e-5f);
  ushort* orow = out + (size_t)row * D_;
#pragma unroll
  for (int q = 0; q < 4; ++q) {
    const float4 g  = *reinterpret_cast<const float4*>(gamma + q * 256 + lane * 4);
    const float4 bt = *reinterpret_cast<const float4*>(beta  + q * 256 + lane * 4);
    ushort4 o;
    o.x = f2b((v[q].x - mean) * rstd * g.x + bt.x);
    o.y = f2b((v[q].y - mean) * rstd * g.y + bt.y);
    o.z = f2b((v[q].z - mean) * rstd * g.z + bt.z);
    o.w = f2b((v[q].w - mean) * rstd * g.w + bt.w);
    *reinterpret_cast<ushort4*>(orow + q * 256 + lane * 4) = o;
  }
}

// ---------------------------------------------------------------------------
// bf16 transpose [R][C] -> [C][R], per batch. 64x64 LDS tile.
// grid (C/64, R/64, B), block 256.
// ---------------------------------------------------------------------------
__global__ __launch_bounds__(256) void transpose_bf16_kernel(
    const ushort* __restrict__ in, ushort* __restrict__ out, int R, int C)
{
  __shared__ ushort lds[64][68];
  const size_t nb = (size_t)blockIdx.z * (size_t)R * C;
  const ushort* ib = in + nb;
  ushort* ob = out + nb;
  const int c0 = blockIdx.x * 64, r0 = blockIdx.y * 64;
  const int t = threadIdx.x;
#pragma unroll
  for (int it = 0; it < 2; ++it) {
    const int r = (t >> 3) + 32 * it;
    const int c = (t & 7) * 8;
    uint4 val = *reinterpret_cast<const uint4*>(ib + (size_t)(r0 + r) * C + c0 + c);
    *reinterpret_cast<uint2*>(&lds[r][c])     = make_uint2(val.x, val.y);
    *reinterpret_cast<uint2*>(&lds[r][c + 4]) = make_uint2(val.z, val.w);
  }
  __syncthreads();
#pragma unroll
  for (int it = 0; it < 2; ++it) {
    const int c  = (t >> 3) + 32 * it;  // output row = original col
    const int rb = (t & 7) * 8;         // original row chunk
    union { ushort u[8]; uint4 v; } pk;
#pragma unroll
    for (int j = 0; j < 8; ++j) pk.u[j] = lds[rb + j][c];
    *reinterpret_cast<uint4*>(ob + (size_t)(c0 + c) * R + r0 + rb) = pk.v;
  }
}

// ---------------------------------------------------------------------------
// qk_softmax v10: 128i x 512t block (halves K-panel staging + barrier count
// per FLOP vs v9's 64i). 8 waves in 2(i) x 4(t); each wave 64i x 128t
// (acc[4][8] = 128 VGPR; __launch_bounds__(512,1) to allow 256 VGPR,
// 1 block/CU, 82KB LDS). Reg-staged dbuf + XOR swizzle (R7 formulas),
// softmax without max-shift (R11). Grid 256, XCD-swizzled.
// ---------------------------------------------------------------------------
__global__ __launch_bounds__(512, 1) void qk_softmax_kernel(
    const ushort* __restrict__ qn,   // [B][NI][D] bf16
    const ushort* __restrict__ kn,   // [B][NT][D] bf16
    ushort* __restrict__ attn_it,    // [B][NI][NT] bf16
    ushort* __restrict__ attn_ti)    // [B][NT][NI] bf16
{
  __shared__ __align__(16) ushort Asm[2][128 * 32];    // 2 x 8KB
  __shared__ __align__(16) ushort Bsm[2][512 * 32];    // 2 x 32KB
  __shared__ __align__(16) float reds[128][4];

  // bijective XCD swizzle (256 blocks, 32 per XCD = 4 consecutive batches)
  const int bid = blockIdx.x;
  const int sid = (bid & 7) * 32 + (bid >> 3);
  const int b   = sid >> 3;            // batch
  const int i0  = (sid & 7) * 128;     // i-block base
  const int tid  = threadIdx.x;
  const int w    = tid >> 6;           // wave 0..7
  const int lane = tid & 63;
  const int lr   = lane & 15;
  const int g    = lane >> 4;
  const int wi   = (w >> 2) * 64;      // wave i-offset (0/64)
  const int wt   = (w & 3) * 128;      // wave t-offset (0..384)

  const ushort* qb = qn + ((size_t)b * NI_ + i0) * D_;
  const ushort* kb = kn + (size_t)b * NT_ * D_;

  const int srow = tid >> 2;           // 0..127
  const int scol = (tid & 3) * 8;
  const int wp = (((tid >> 6) << 6) | (((tid >> 2) & 15) << 2)
                | ((tid & 3) ^ ((tid >> 3) & 3))) * 8;
  const int chunkLane = ((lane & 15) << 2) | ((lane >> 4) ^ ((lane >> 1) & 3));

  uint4 ra, rb0, rb1, rb2, rb3;
  auto LOAD = [&](int t) {
    const int ko = t * 32 + scol;
    ra  = *reinterpret_cast<const uint4*>(qb + (size_t)srow * D_ + ko);
    rb0 = *reinterpret_cast<const uint4*>(kb + (size_t)(srow      ) * D_ + ko);
    rb1 = *reinterpret_cast<const uint4*>(kb + (size_t)(srow + 128) * D_ + ko);
    rb2 = *reinterpret_cast<const uint4*>(kb + (size_t)(srow + 256) * D_ + ko);
    rb3 = *reinterpret_cast<const uint4*>(kb + (size_t)(srow + 384) * D_ + ko);
  };
  auto WRITE = [&](int nb) {
    *reinterpret_cast<uint4*>(&Asm[nb][wp        ]) = ra;
    *reinterpret_cast<uint4*>(&Bsm[nb][wp        ]) = rb0;   // rows 0-127
    *reinterpret_cast<uint4*>(&Bsm[nb][wp +  4096]) = rb1;   // +8 blocks
    *reinterpret_cast<uint4*>(&Bsm[nb][wp +  8192]) = rb2;
    *reinterpret_cast<uint4*>(&Bsm[nb][wp + 12288]) = rb3;
  };

  f32x4 acc[4][8];
#pragma unroll
  for (int i = 0; i < 4; ++i)
#pragma unroll
    for (int n = 0; n < 8; ++n) acc[i][n] = (f32x4){0.f, 0.f, 0.f, 0.f};

  LOAD(0); WRITE(0); __syncthreads();
  const int nst = D_ / 32;   // 32
  int cur = 0;
  for (int t = 0; t < nst; ++t) {
    if (t + 1 < nst) LOAD(t + 1);
    const ushort* As = Asm[cur];
    const ushort* Bs = Bsm[cur];
    bf16x8 af[4], bf[8];
#pragma unroll
    for (int i = 0; i < 4; ++i)
      af[i] = *reinterpret_cast<const bf16x8*>(
          As + (((w >> 2) * 4 + i) * 64 + chunkLane) * 8);
#pragma unroll
    for (int n = 0; n < 8; ++n)
      bf[n] = *reinterpret_cast<const bf16x8*>(
          Bs + (((w & 3) * 8 + n) * 64 + chunkLane) * 8);
#pragma unroll
    for (int i = 0; i < 4; ++i)
#pragma unroll
      for (int n = 0; n < 8; ++n)
        acc[i][n] = __builtin_amdgcn_mfma_f32_16x16x32_bf16(af[i], bf[n], acc[i][n], 0, 0, 0);
    __syncthreads();
    if (t + 1 < nst) WRITE(cur ^ 1);
    __syncthreads();
    cur ^= 1;
  }

  // ---- softmax over full t (512) per i-row, no max-shift ----
  // C/D: local row = wi + i*16 + g*4 + r, col = wt + n*16 + lr
  const float c1 = 0.03125f * 1.44269504f;  // scale * log2(e)

  float sm[4][4];
#pragma unroll
  for (int i = 0; i < 4; ++i)
#pragma unroll
    for (int r = 0; r < 4; ++r) sm[i][r] = 0.f;
#pragma unroll
  for (int i = 0; i < 4; ++i)
#pragma unroll
    for (int n = 0; n < 8; ++n)
#pragma unroll
      for (int r = 0; r < 4; ++r) {
        const float p = exp2f(acc[i][n][r] * c1);
        acc[i][n][r] = p;
        sm[i][r] += p;
      }
#pragma unroll
  for (int i = 0; i < 4; ++i)
#pragma unroll
    for (int r = 0; r < 4; ++r) {
      float s = sm[i][r];
      s += __shfl_xor(s, 1);
      s += __shfl_xor(s, 2);
      s += __shfl_xor(s, 4);
      s += __shfl_xor(s, 8);
      sm[i][r] = s;
    }
  if (lr == 0) {
#pragma unroll
    for (int i = 0; i < 4; ++i)
#pragma unroll
      for (int r = 0; r < 4; ++r) reds[wi + i * 16 + g * 4 + r][w & 3] = sm[i][r];
  }
  __syncthreads();
  float inv[4][4];
#pragma unroll
  for (int i = 0; i < 4; ++i)
#pragma unroll
    for (int r = 0; r < 4; ++r) {
      const float4 a0 = *reinterpret_cast<const float4*>(&reds[wi + i * 16 + g * 4 + r][0]);
      inv[i][r] = 1.f / (a0.x + a0.y + a0.z + a0.w);
    }

  // ---- write attn in both layouts ----
#pragma unroll
  for (int i = 0; i < 4; ++i) {
    const int rbase = i0 + wi + i * 16 + g * 4;
#pragma unroll
    for (int n = 0; n < 8; ++n) {
      const int tcol = wt + n * 16 + lr;
      ushort4 pk;
      pk.x = f2b(acc[i][n][0] * inv[i][0]);
      pk.y = f2b(acc[i][n][1] * inv[i][1]);
      pk.z = f2b(acc[i][n][2] * inv[i][2]);
      pk.w = f2b(acc[i][n][3] * inv[i][3]);
      ushort* it_p = attn_it + ((size_t)b * NI_ + rbase) * NT_ + tcol;
      it_p[0 * NT_] = pk.x;
      it_p[1 * NT_] = pk.y;
      it_p[2 * NT_] = pk.z;
      it_p[3 * NT_] = pk.w;
      *reinterpret_cast<ushort4*>(attn_ti + ((size_t)b * NT_ + tcol) * NI_ + rbase) = pk;
    }
  }
}

// ---------------------------------------------------------------------------
// bt_gemm v9 (FROZEN from R11): reg-staged dbuf, XOR-swizzled LDS, chunked
// bijective XCD swizzle. BK=32, 128x128, 4 waves. grid 1D, block 256.
// ---------------------------------------------------------------------------
__global__ __launch_bounds__(256) void bt_gemm_add_kernel(
    const ushort* __restrict__ A,   // [B][M][K] bf16
    const ushort* __restrict__ Bm,  // [B][N][K] bf16
    const float* __restrict__ add,  // [B][M][N] f32
    float* __restrict__ out,        // [B][M][N] f32
    int M, int N, int K)
{
  __shared__ __align__(16) ushort Asm[2][128 * 32];   // 2 x 8KB
  __shared__ __align__(16) ushort Bsm[2][128 * 32];   // 2 x 8KB

  const int nwx = N >> 7, nwy = M >> 7;
  const int per = (nwx * nwy * B_) >> 3;         // blocks per XCD
  const int sid = (blockIdx.x & 7) * per + (blockIdx.x >> 3);
  const int b   = sid / (nwx * nwy);
  const int rem = sid - b * (nwx * nwy);
  const int m0  = (rem / nwx) * 128;
  const int n0  = (rem % nwx) * 128;

  const int tid  = threadIdx.x;
  const int w    = tid >> 6;
  const int lane = tid & 63;
  const int lr   = lane & 15;
  const int g    = lane >> 4;

  const ushort* Ab = A  + ((size_t)b * M + m0) * K;
  const ushort* Bb = Bm + ((size_t)b * N + n0) * K;

  const int srow = tid >> 2;           // 0..63
  const int scol = (tid & 3) * 8;
  const int wp = (((tid >> 6) << 6) | (((tid >> 2) & 15) << 2)
                | ((tid & 3) ^ ((tid >> 3) & 3))) * 8;
  const int chunkLane = ((lane & 15) << 2) | ((lane >> 4) ^ ((lane >> 1) & 3));

  uint4 ra0, ra1, rbx0, rbx1;
  auto LOAD = [&](int t) {
    const int ko = t * 32 + scol;
    ra0  = *reinterpret_cast<const uint4*>(Ab + (size_t)(srow     ) * K + ko);
    ra1  = *reinterpret_cast<const uint4*>(Ab + (size_t)(srow + 64) * K + ko);
    rbx0 = *reinterpret_cast<const uint4*>(Bb + (size_t)(srow     ) * K + ko);
    rbx1 = *reinterpret_cast<const uint4*>(Bb + (size_t)(srow + 64) * K + ko);
  };
  auto WRITE = [&](int nb) {
    *reinterpret_cast<uint4*>(&Asm[nb][wp       ]) = ra0;
    *reinterpret_cast<uint4*>(&Asm[nb][wp + 2048]) = ra1;
    *reinterpret_cast<uint4*>(&Bsm[nb][wp       ]) = rbx0;
    *reinterpret_cast<uint4*>(&Bsm[nb][wp + 2048]) = rbx1;
  };

  f32x4 acc[4][4];
#pragma unroll
  for (int i = 0; i < 4; ++i)
#pragma unroll
    for (int j = 0; j < 4; ++j) acc[i][j] = (f32x4){0.f, 0.f, 0.f, 0.f};

  LOAD(0); WRITE(0); __syncthreads();
  const int nst = K / 32;
  int cur = 0;
  for (int t = 0; t < nst; ++t) {
    if (t + 1 < nst) LOAD(t + 1);
    const ushort* As = Asm[cur];
    const ushort* Bs = Bsm[cur];
    bf16x8 af[4], bf[4];
#pragma unroll
    for (int i = 0; i < 4; ++i)
      af[i] = *reinterpret_cast<const bf16x8*>(
          As + (((w >> 1) * 4 + i) * 64 + chunkLane) * 8);
#pragma unroll
    for (int j = 0; j < 4; ++j)
      bf[j] = *reinterpret_cast<const bf16x8*>(
          Bs + (((w & 1) * 4 + j) * 64 + chunkLane) * 8);
#pragma unroll
    for (int i = 0; i < 4; ++i)
#pragma unroll
      for (int j = 0; j < 4; ++j)
        acc[i][j] = __builtin_amdgcn_mfma_f32_16x16x32_bf16(af[i], bf[j], acc[i][j], 0, 0, 0);
    __syncthreads();
    if (t + 1 < nst) WRITE(cur ^ 1);
    __syncthreads();
    cur ^= 1;
  }

  const size_t ob = (size_t)b * M * N;
  const int rbase = m0 + (w >> 1) * 64 + g * 4;
#pragma unroll
  for (int i = 0; i < 4; ++i)
#pragma unroll
    for (int j = 0; j < 4; ++j) {
      const int c = n0 + (w & 1) * 64 + j * 16 + lr;
#pragma unroll
      for (int r = 0; r < 4; ++r) {
        const size_t idx = ob + (size_t)(rbase + i * 16 + r) * N + c;
        out[idx] = add[idx] + acc[i][j][r];
      }
    }
}

// ---------------------------------------------------------------------------
// Schedule (buffer aliasing; ws_size >= 96 MB, observed ~768MB):
//   imn in out1 region, txn in out0 region (dead before outputs written);
//   ws: [attn_ti][attn_it][txnT]; imnT reuses attn_it+txnT after GEMM5.
// ---------------------------------------------------------------------------
extern "C" void kernel_launch(void* const* d_in, const int* in_sizes, int n_in,
                              void* d_out, int out_size, void* d_ws, size_t ws_size,
                              hipStream_t stream) {
  const float* imgf  = (const float*)d_in[0];
  const float* txtf  = (const float*)d_in[1];
  const float* gamma = (const float*)d_in[2];
  const float* beta  = (const float*)d_in[3];

  float* out0 = (float*)d_out;                       // [B][NI][D] f32
  float* out1 = out0 + (size_t)B_ * NI_ * D_;        // [B][NT][D] f32

  const size_t SZ = (size_t)B_ * NT_ * NI_ * 2;      // 33,554,432 B
  char* ws = (char*)d_ws;
  ushort* attn_ti = (ushort*)ws;                     // [B][NT][NI]
  ushort* attn_it = (ushort*)(ws + SZ);              // [B][NI][NT]
  ushort* txnT    = (ushort*)(ws + 2 * SZ);          // [B][D][NT]
  ushort* imnT    = (ushort*)(ws + SZ);              // [B][D][NI] (aliases attn_it+txnT)
  ushort* imn     = (ushort*)out1;                   // [B][NI][D] bf16 (scratch in out1)
  ushort* txn     = (ushort*)out0;                   // [B][NT][D] bf16 (scratch in out0)

  // 1-2: layernorms -> bf16
  ln_bf16_kernel<<<(B_ * NI_) / 4, 256, 0, stream>>>(imgf, gamma, beta, imn);
  ln_bf16_kernel<<<(B_ * NT_) / 4, 256, 0, stream>>>(txtf, gamma, beta, txn);
  // 3: QK^T + softmax -> attn in both layouts (256 blocks, XCD-swizzled)
  qk_softmax_kernel<<<(NI_ / 128) * B_, 512, 0, stream>>>(imn, txn, attn_it, attn_ti);
  // 4: text_norm^T
  transpose_bf16_kernel<<<dim3(D_ / 64, NT_ / 64, B_), 256, 0, stream>>>(txn, txnT, NT_, D_);
  // 5: out0 = image + attn @ text_norm   (overwrites txn scratch — dead)
  bt_gemm_add_kernel<<<(D_ / 128) * (NI_ / 128) * B_, 256, 0, stream>>>(
      attn_it, txnT, imgf, out0, NI_, D_, NT_);
  // 6: image_norm^T (overwrites attn_it + txnT — dead)
  transpose_bf16_kernel<<<dim3(D_ / 64, NI_ / 64, B_), 256, 0, stream>>>(imn, imnT, NI_, D_);
  // 7: out1 = text + attn^T @ image_norm (overwrites imn scratch — dead)
  bt_gemm_add_kernel<<<(D_ / 128) * (NT_ / 128) * B_, 256, 0, stream>>>(
      attn_ti, imnT, txtf, out1, NT_, D_, NI_);
}

// Round 13
// 319.225 us; speedup vs baseline: 1.0071x; 1.0071x over previous
//
#include <hip/hip_runtime.h>
#include <hip/hip_bf16.h>

// Problem constants
#define B_  32
#define NI_ 1024
#define NT_ 512
#define D_  1024

typedef __attribute__((ext_vector_type(8))) short bf16x8;   // 8 bf16 = 4 VGPRs
typedef __attribute__((ext_vector_type(4))) float f32x4;    // MFMA accumulator

// round-to-nearest-even f32 -> bf16 (values are finite here)
__device__ __forceinline__ ushort f2b(float f) {
  unsigned u = __builtin_bit_cast(unsigned, f);
  u = (u + 0x7FFFu + ((u >> 16) & 1u)) >> 16;
  return (ushort)u;
}

// async global->LDS 16B copy: per-lane global address, LDS dest is
// wave-uniform base + lane*16.
__device__ __forceinline__ void gll16(const ushort* g, ushort* l) {
  __builtin_amdgcn_global_load_lds(
      (const __attribute__((address_space(1))) void*)g,
      (__attribute__((address_space(3))) void*)l, 16, 0, 0);
}

#define VMWAIT(N) asm volatile("s_waitcnt vmcnt(" #N ")" ::: "memory")

// ---------------------------------------------------------------------------
// LayerNorm over D=1024, fp32 in -> bf16 out. One wave per row, 4 rows/block.
// ---------------------------------------------------------------------------
__global__ __launch_bounds__(256) void ln_bf16_kernel(
    const float* __restrict__ x, const float* __restrict__ gamma,
    const float* __restrict__ beta, ushort* __restrict__ out)
{
  const int row  = blockIdx.x * 4 + (threadIdx.x >> 6);
  const int lane = threadIdx.x & 63;
  const float* xr = x + (size_t)row * D_;
  float4 v[4];
  float s = 0.f, sq = 0.f;
#pragma unroll
  for (int q = 0; q < 4; ++q) {
    v[q] = *reinterpret_cast<const float4*>(xr + q * 256 + lane * 4);
    s  += v[q].x + v[q].y + v[q].z + v[q].w;
    sq += v[q].x*v[q].x + v[q].y*v[q].y + v[q].z*v[q].z + v[q].w*v[q].w;
  }
#pragma unroll
  for (int m = 1; m < 64; m <<= 1) {
    s  += __shfl_xor(s,  m);
    sq += __shfl_xor(sq, m);
  }
  const float mean = s * (1.f / D_);
  const float rstd = rsqrtf(sq * (1.f / D_) - mean * mean + 1e-5f);
  ushort* orow = out + (size_t)row * D_;
#pragma unroll
  for (int q = 0; q < 4; ++q) {
    const float4 g  = *reinterpret_cast<const float4*>(gamma + q * 256 + lane * 4);
    const float4 bt = *reinterpret_cast<const float4*>(beta  + q * 256 + lane * 4);
    ushort4 o;
    o.x = f2b((v[q].x - mean) * rstd * g.x + bt.x);
    o.y = f2b((v[q].y - mean) * rstd * g.y + bt.y);
    o.z = f2b((v[q].z - mean) * rstd * g.z + bt.z);
    o.w = f2b((v[q].w - mean) * rstd * g.w + bt.w);
    *reinterpret_cast<ushort4*>(orow + q * 256 + lane * 4) = o;
  }
}

// ---------------------------------------------------------------------------
// bf16 transpose [R][C] -> [C][R], per batch. 64x64 LDS tile.
// grid (C/64, R/64, B), block 256.
// ---------------------------------------------------------------------------
__global__ __launch_bounds__(256) void transpose_bf16_kernel(
    const ushort* __restrict__ in, ushort* __restrict__ out, int R, int C)
{
  __shared__ ushort lds[64][68];
  const size_t nb = (size_t)blockIdx.z * (size_t)R * C;
  const ushort* ib = in + nb;
  ushort* ob = out + nb;
  const int c0 = blockIdx.x * 64, r0 = blockIdx.y * 64;
  const int t = threadIdx.x;
#pragma unroll
  for (int it = 0; it < 2; ++it) {
    const int r = (t >> 3) + 32 * it;
    const int c = (t & 7) * 8;
    uint4 val = *reinterpret_cast<const uint4*>(ib + (size_t)(r0 + r) * C + c0 + c);
    *reinterpret_cast<uint2*>(&lds[r][c])     = make_uint2(val.x, val.y);
    *reinterpret_cast<uint2*>(&lds[r][c + 4]) = make_uint2(val.z, val.w);
  }
  __syncthreads();
#pragma unroll
  for (int it = 0; it < 2; ++it) {
    const int c  = (t >> 3) + 32 * it;  // output row = original col
    const int rb = (t & 7) * 8;         // original row chunk
    union { ushort u[8]; uint4 v; } pk;
#pragma unroll
    for (int j = 0; j < 8; ++j) pk.u[j] = lds[rb + j][c];
    *reinterpret_cast<uint4*>(ob + (size_t)(c0 + c) * R + r0 + rb) = pk.v;
  }
}

// ---------------------------------------------------------------------------
// qk_softmax v9 (FROZEN from R11, the 320us config): reg-staged dbuf,
// XOR-swizzled LDS, softmax without max-shift.
// Block = 64 i x 512 t, 8 waves. Grid 512, XCD-swizzled.
// ---------------------------------------------------------------------------
__global__ __launch_bounds__(512) void qk_softmax_kernel(
    const ushort* __restrict__ qn,   // [B][NI][D] bf16
    const ushort* __restrict__ kn,   // [B][NT][D] bf16
    ushort* __restrict__ attn_it,    // [B][NI][NT] bf16
    ushort* __restrict__ attn_ti)    // [B][NT][NI] bf16
{
  __shared__ __align__(16) ushort Asm[2][64 * 32];     // 2 x 4KB
  __shared__ __align__(16) ushort Bsm[2][512 * 32];    // 2 x 32KB
  __shared__ __align__(16) float reds[64][8];

  const int bid = blockIdx.x;
  const int sid = (bid & 7) * 64 + (bid >> 3);
  const int b   = sid >> 4;            // batch
  const int i0  = (sid & 15) * 64;     // i-block base
  const int tid  = threadIdx.x;
  const int w    = tid >> 6;           // wave 0..7 -> t-range w*64
  const int lane = tid & 63;
  const int lr   = lane & 15;
  const int g    = lane >> 4;

  const ushort* qb = qn + ((size_t)b * NI_ + i0) * D_;
  const ushort* kb = kn + (size_t)b * NT_ * D_;

  const int srow = tid >> 2;
  const int scol = (tid & 3) * 8;
  const int wp = (((tid >> 6) << 6) | (((tid >> 2) & 15) << 2)
                | ((tid & 3) ^ ((tid >> 3) & 3))) * 8;
  const int chunkLane = ((lane & 15) << 2) | ((lane >> 4) ^ ((lane >> 1) & 3));

  uint4 ra, rb0, rb1, rb2, rb3;
  auto LOAD = [&](int t) {
    const int ko = t * 32 + scol;
    if (tid < 256) ra = *reinterpret_cast<const uint4*>(qb + (size_t)srow * D_ + ko);
    rb0 = *reinterpret_cast<const uint4*>(kb + (size_t)(srow      ) * D_ + ko);
    rb1 = *reinterpret_cast<const uint4*>(kb + (size_t)(srow + 128) * D_ + ko);
    rb2 = *reinterpret_cast<const uint4*>(kb + (size_t)(srow + 256) * D_ + ko);
    rb3 = *reinterpret_cast<const uint4*>(kb + (size_t)(srow + 384) * D_ + ko);
  };
  auto WRITE = [&](int nb) {
    if (tid < 256) *reinterpret_cast<uint4*>(&Asm[nb][wp]) = ra;
    *reinterpret_cast<uint4*>(&Bsm[nb][wp        ]) = rb0;
    *reinterpret_cast<uint4*>(&Bsm[nb][wp +  4096]) = rb1;
    *reinterpret_cast<uint4*>(&Bsm[nb][wp +  8192]) = rb2;
    *reinterpret_cast<uint4*>(&Bsm[nb][wp + 12288]) = rb3;
  };

  f32x4 acc[4][4];
#pragma unroll
  for (int i = 0; i < 4; ++i)
#pragma unroll
    for (int j = 0; j < 4; ++j) acc[i][j] = (f32x4){0.f, 0.f, 0.f, 0.f};

  LOAD(0); WRITE(0); __syncthreads();
  const int nst = D_ / 32;   // 32
  int cur = 0;
  for (int t = 0; t < nst; ++t) {
    if (t + 1 < nst) LOAD(t + 1);
    const ushort* As = Asm[cur];
    const ushort* Bs = Bsm[cur];
    bf16x8 af[4], bf[4];
#pragma unroll
    for (int i = 0; i < 4; ++i)
      af[i] = *reinterpret_cast<const bf16x8*>(As + (i * 64 + chunkLane) * 8);
#pragma unroll
    for (int j = 0; j < 4; ++j)
      bf[j] = *reinterpret_cast<const bf16x8*>(Bs + ((w * 4 + j) * 64 + chunkLane) * 8);
#pragma unroll
    for (int i = 0; i < 4; ++i)
#pragma unroll
      for (int j = 0; j < 4; ++j)
        acc[i][j] = __builtin_amdgcn_mfma_f32_16x16x32_bf16(af[i], bf[j], acc[i][j], 0, 0, 0);
    __syncthreads();
    if (t + 1 < nst) WRITE(cur ^ 1);
    __syncthreads();
    cur ^= 1;
  }

  const float c1 = 0.03125f * 1.44269504f;  // scale * log2(e)

  float sm[4][4];
#pragma unroll
  for (int i = 0; i < 4; ++i)
#pragma unroll
    for (int r = 0; r < 4; ++r) sm[i][r] = 0.f;
#pragma unroll
  for (int i = 0; i < 4; ++i)
#pragma unroll
    for (int j = 0; j < 4; ++j)
#pragma unroll
      for (int r = 0; r < 4; ++r) {
        const float p = exp2f(acc[i][j][r] * c1);
        acc[i][j][r] = p;
        sm[i][r] += p;
      }
#pragma unroll
  for (int i = 0; i < 4; ++i)
#pragma unroll
    for (int r = 0; r < 4; ++r) {
      float s = sm[i][r];
      s += __shfl_xor(s, 1);
      s += __shfl_xor(s, 2);
      s += __shfl_xor(s, 4);
      s += __shfl_xor(s, 8);
      sm[i][r] = s;
    }
  if (lr == 0) {
#pragma unroll
    for (int i = 0; i < 4; ++i)
#pragma unroll
      for (int r = 0; r < 4; ++r) reds[i * 16 + g * 4 + r][w] = sm[i][r];
  }
  __syncthreads();
  float inv[4][4];
#pragma unroll
  for (int i = 0; i < 4; ++i)
#pragma unroll
    for (int r = 0; r < 4; ++r) {
      const int row = i * 16 + g * 4 + r;
      const float4 a0 = *reinterpret_cast<const float4*>(&reds[row][0]);
      const float4 a1 = *reinterpret_cast<const float4*>(&reds[row][4]);
      inv[i][r] = 1.f / (a0.x + a0.y + a0.z + a0.w + a1.x + a1.y + a1.z + a1.w);
    }

#pragma unroll
  for (int i = 0; i < 4; ++i) {
    const int rbase = i0 + i * 16 + g * 4;
#pragma unroll
    for (int j = 0; j < 4; ++j) {
      const int tcol = w * 64 + j * 16 + lr;
      ushort4 pk;
      pk.x = f2b(acc[i][j][0] * inv[i][0]);
      pk.y = f2b(acc[i][j][1] * inv[i][1]);
      pk.z = f2b(acc[i][j][2] * inv[i][2]);
      pk.w = f2b(acc[i][j][3] * inv[i][3]);
      ushort* it_p = attn_it + ((size_t)b * NI_ + rbase) * NT_ + tcol;
      it_p[0 * NT_] = pk.x;
      it_p[1 * NT_] = pk.y;
      it_p[2 * NT_] = pk.z;
      it_p[3 * NT_] = pk.w;
      *reinterpret_cast<ushort4*>(attn_ti + ((size_t)b * NT_ + tcol) * NI_ + rbase) = pk;
    }
  }
}

// ---------------------------------------------------------------------------
// bt_gemm v10: fine-interleaved counted-vmcnt pipeline (T3+T4+T5 mechanism,
// the form m196 proved; R8 was the coarse variant m196 proves HURTS).
// 256x256 tile, 8 waves (2M x 4N), per-wave 128x64 out (acc[8][4]).
// BK=32 per K-tile, 2 phases/tile (M-half h), 16 MFMA each.
// LDS: 2 dbuf x (A[256][32] + B[256][32]) = 64KB, fragment-order chunks
// (chunk = rowblk*64 + g*16 + lr; frag read = rowblk*64 + lane: lane-linear,
// conflict-free, gll-compatible — R5-verified formulas).
// Staging of tile t+1 interleaved into tile t's phases in dependency order:
// phase0 issues B(t+1) [2 gll], phase1 issues A-h0(t+1), A-h1(t+1) [2 gll].
// Counted waits (per-wave vmcnt + barrier publishes cross-wave):
//   tile boundary: vmcnt(1)  (B + A-h0 of tile t done; A-h1 stays in flight)
//   mid-tile:      vmcnt(2)  (A-h1 of t done; B(t+1) stays in flight)
// grid 1D = (N/256)*(M/256)*B (div by 8), chunked XCD swizzle, block 512.
// ---------------------------------------------------------------------------
__global__ __launch_bounds__(512) void bt_gemm_add_kernel(
    const ushort* __restrict__ A,   // [B][M][K] bf16
    const ushort* __restrict__ Bm,  // [B][N][K] bf16
    const float* __restrict__ add,  // [B][M][N] f32
    float* __restrict__ out,        // [B][M][N] f32
    int M, int N, int K)
{
  __shared__ __align__(16) ushort Asm[2][256 * 32];   // 2 x 16KB
  __shared__ __align__(16) ushort Bsm[2][256 * 32];   // 2 x 16KB

  const int nwx = N >> 8, nwy = M >> 8;
  const int per = (nwx * nwy * B_) >> 3;         // blocks per XCD
  const int sid = (blockIdx.x & 7) * per + (blockIdx.x >> 3);
  const int b   = sid / (nwx * nwy);
  const int rem = sid - b * (nwx * nwy);
  const int m0  = (rem / nwx) * 256;
  const int n0  = (rem % nwx) * 256;

  const int tid  = threadIdx.x;
  const int w    = tid >> 6;         // 0..7
  const int lane = tid & 63;
  const int lr   = lane & 15;
  const int g    = lane >> 4;
  const int wm   = w >> 2;           // 0..1  (M-half of 256)
  const int wn   = w & 3;            // 0..3  (N-quarter)

  const ushort* Ab = A  + ((size_t)b * M + m0) * K;
  const ushort* Bb = Bm + ((size_t)b * N + n0) * K;
  const int nst = K >> 5;            // 16 (gemm5) / 32 (gemm7)

  // stage rowblk rb (16 rows x 32 k) of K-tile kt into buffer nb.
  // chunk c = rb*64 + lane; source row = rb*16 + lr, k = kt*32 + g*8.
  auto GLL_A = [&](int nb, int kt, int rb) {
    gll16(Ab + (size_t)(rb * 16 + lr) * K + kt * 32 + g * 8,
          &Asm[nb][rb * 64 * 8]);
  };
  auto GLL_B = [&](int nb, int kt, int rb) {
    gll16(Bb + (size_t)(rb * 16 + lr) * K + kt * 32 + g * 8,
          &Bsm[nb][rb * 64 * 8]);
  };
  // per-wave staging assignments (issue order: B,B,A-h0,A-h1)
  const int rbA0 = (w & 3) + ((w >> 2) << 3);   // h0 rowblks {0-3,8-11}

  f32x4 acc[8][4];
#pragma unroll
  for (int i = 0; i < 8; ++i)
#pragma unroll
    for (int j = 0; j < 4; ++j) acc[i][j] = (f32x4){0.f, 0.f, 0.f, 0.f};

  // prologue: tile 0 into buf 0 (order B,B,Ah0,Ah1)
  GLL_B(0, 0, w); GLL_B(0, 0, w + 8);
  GLL_A(0, 0, rbA0); GLL_A(0, 0, rbA0 + 4);

  for (int t = 0; t < nst; ++t) {
    const int par = t & 1;
    const ushort* As = Asm[par];
    const ushort* Bs = Bsm[par];

    // tile boundary: B + A-h0 of tile t resident (A-h1 may remain in flight)
    VMWAIT(1);
    __builtin_amdgcn_sched_barrier(0);
    __builtin_amdgcn_s_barrier();

    // ---- phase 0: h = 0 ----
    bf16x8 bf[4], af[4];
#pragma unroll
    for (int j = 0; j < 4; ++j)
      bf[j] = *reinterpret_cast<const bf16x8*>(Bs + ((wn * 4 + j) * 64 + lane) * 8);
#pragma unroll
    for (int i = 0; i < 4; ++i)
      af[i] = *reinterpret_cast<const bf16x8*>(As + ((wm * 8 + i) * 64 + lane) * 8);
    if (t + 1 < nst) { GLL_B(par ^ 1, t + 1, w); GLL_B(par ^ 1, t + 1, w + 8); }
    __builtin_amdgcn_s_barrier();
    __builtin_amdgcn_s_setprio(1);
#pragma unroll
    for (int i = 0; i < 4; ++i)
#pragma unroll
      for (int j = 0; j < 4; ++j)
        acc[i][j] = __builtin_amdgcn_mfma_f32_16x16x32_bf16(af[i], bf[j], acc[i][j], 0, 0, 0);
    __builtin_amdgcn_s_setprio(0);

    // mid-tile: A-h1 of tile t resident (B of t+1 stays in flight)
    if (t + 1 < nst) { VMWAIT(2); } else { VMWAIT(0); }
    __builtin_amdgcn_sched_barrier(0);
    __builtin_amdgcn_s_barrier();

    // ---- phase 1: h = 1 (B frags reused from phase 0) ----
#pragma unroll
    for (int i = 0; i < 4; ++i)
      af[i] = *reinterpret_cast<const bf16x8*>(As + ((wm * 8 + 4 + i) * 64 + lane) * 8);
    if (t + 1 < nst) { GLL_A(par ^ 1, t + 1, rbA0); GLL_A(par ^ 1, t + 1, rbA0 + 4); }
    __builtin_amdgcn_s_barrier();
    __builtin_amdgcn_s_setprio(1);
#pragma unroll
    for (int i = 0; i < 4; ++i)
#pragma unroll
      for (int j = 0; j < 4; ++j)
        acc[4 + i][j] = __builtin_amdgcn_mfma_f32_16x16x32_bf16(af[i], bf[j], acc[4 + i][j], 0, 0, 0);
    __builtin_amdgcn_s_setprio(0);
  }

  // ---- epilogue: out = add + acc ----
  const size_t ob = (size_t)b * M * N;
#pragma unroll
  for (int hi = 0; hi < 8; ++hi)
#pragma unroll
    for (int j = 0; j < 4; ++j) {
      const int mrow = m0 + wm * 128 + hi * 16 + g * 4;
      const int c    = n0 + wn * 64 + j * 16 + lr;
#pragma unroll
      for (int r = 0; r < 4; ++r) {
        const size_t idx = ob + (size_t)(mrow + r) * N + c;
        out[idx] = add[idx] + acc[hi][j][r];
      }
    }
}

// ---------------------------------------------------------------------------
// Schedule (buffer aliasing; ws_size >= 96 MB, observed ~768MB):
//   imn in out1 region, txn in out0 region (dead before outputs written);
//   ws: [attn_ti][attn_it][txnT]; imnT reuses attn_it+txnT after GEMM5.
// ---------------------------------------------------------------------------
extern "C" void kernel_launch(void* const* d_in, const int* in_sizes, int n_in,
                              void* d_out, int out_size, void* d_ws, size_t ws_size,
                              hipStream_t stream) {
  const float* imgf  = (const float*)d_in[0];
  const float* txtf  = (const float*)d_in[1];
  const float* gamma = (const float*)d_in[2];
  const float* beta  = (const float*)d_in[3];

  float* out0 = (float*)d_out;                       // [B][NI][D] f32
  float* out1 = out0 + (size_t)B_ * NI_ * D_;        // [B][NT][D] f32

  const size_t SZ = (size_t)B_ * NT_ * NI_ * 2;      // 33,554,432 B
  char* ws = (char*)d_ws;
  ushort* attn_ti = (ushort*)ws;                     // [B][NT][NI]
  ushort* attn_it = (ushort*)(ws + SZ);              // [B][NI][NT]
  ushort* txnT    = (ushort*)(ws + 2 * SZ);          // [B][D][NT]
  ushort* imnT    = (ushort*)(ws + SZ);              // [B][D][NI] (aliases attn_it+txnT)
  ushort* imn     = (ushort*)out1;                   // [B][NI][D] bf16 (scratch in out1)
  ushort* txn     = (ushort*)out0;                   // [B][NT][D] bf16 (scratch in out0)

  // 1-2: layernorms -> bf16
  ln_bf16_kernel<<<(B_ * NI_) / 4, 256, 0, stream>>>(imgf, gamma, beta, imn);
  ln_bf16_kernel<<<(B_ * NT_) / 4, 256, 0, stream>>>(txtf, gamma, beta, txn);
  // 3: QK^T + softmax -> attn in both layouts (512 blocks, XCD-swizzled)
  qk_softmax_kernel<<<(NI_ / 64) * B_, 512, 0, stream>>>(imn, txn, attn_it, attn_ti);
  // 4: text_norm^T
  transpose_bf16_kernel<<<dim3(D_ / 64, NT_ / 64, B_), 256, 0, stream>>>(txn, txnT, NT_, D_);
  // 5: out0 = image + attn @ text_norm   (overwrites txn scratch — dead)
  bt_gemm_add_kernel<<<(D_ / 256) * (NI_ / 256) * B_, 512, 0, stream>>>(
      attn_it, txnT, imgf, out0, NI_, D_, NT_);
  // 6: image_norm^T (overwrites attn_it + txnT — dead)
  transpose_bf16_kernel<<<dim3(D_ / 64, NI_ / 64, B_), 256, 0, stream>>>(imn, imnT, NI_, D_);
  // 7: out1 = text + attn^T @ image_norm (overwrites imn scratch — dead)
  bt_gemm_add_kernel<<<(D_ / 256) * (NT_ / 256) * B_, 512, 0, stream>>>(
      attn_ti, imnT, txtf, out1, NT_, D_, NI_);
}